// Round 7
// baseline (226.177 us; speedup 1.0000x reference)
//
#include <hip/hip_runtime.h>

#define BATCH 512
#define NNODE 200
#define CIN   200
#define HID   128
#define IPY   232   // slab row stride (shorts): conflict-free ds_read_b128 (2-way max)
#define KCH   7     // 7 K-chunks of 32 (cover 224 >= 200)
#define NWAVE 13    // 13 waves = 13 m/j-tiles, 832 threads

typedef __attribute__((ext_vector_type(4))) float  f32x4;
typedef __attribute__((ext_vector_type(4))) int    i32x4;
typedef __attribute__((ext_vector_type(8))) short  sh8;
typedef __attribute__((ext_vector_type(4))) short  sh4;
typedef __attribute__((ext_vector_type(8))) __bf16 bf16x8;

__device__ __forceinline__ short f2bf(float x) {
  union { float f; unsigned u; } v; v.f = x;
  unsigned r = v.u + 0x7FFFu + ((v.u >> 16) & 1u);   // RNE
  return (short)(r >> 16);
}
__device__ __forceinline__ float bf2f(short s) {
  union { unsigned u; float f; } v; v.u = ((unsigned)(unsigned short)s) << 16;
  return v.f;
}
__device__ __forceinline__ f32x4 mfma16(sh8 a, sh8 b, f32x4 c) {
  return __builtin_amdgcn_mfma_f32_16x16x32_bf16(
      __builtin_bit_cast(bf16x8, a), __builtin_bit_cast(bf16x8, b), c, 0, 0, 0);
}
__device__ __forceinline__ f32x4 mfma16i(sh8 a, i32x4 b, f32x4 c) {
  return __builtin_amdgcn_mfma_f32_16x16x32_bf16(
      __builtin_bit_cast(bf16x8, a), __builtin_bit_cast(bf16x8, b), c, 0, 0, 0);
}
// expand 8 adjacency bits -> 4 dwords of packed {bf16(b_even)|bf16(b_odd)<<16}
__device__ __forceinline__ i32x4 expand8(unsigned byte_) {
  i32x4 w;
#pragma unroll
  for (int h = 0; h < 4; ++h) {
    unsigned p = byte_ >> (2 * h);
    unsigned d = ((p & 1u) ? 0x3F80u : 0u) | ((p & 2u) ? 0x3F800000u : 0u);
    w[h] = (int)d;
  }
  return w;
}

// ---------- k_prep: W1 -> fragment-linear W1F[ft][k][lane][8 bf16] (57,344 B) ----------
// Wave-load of (ft,k) fragment = base + lane*16B: ONE coalesced segment, L1/L2-resident,
// shared by all 512 blocks. Replaces the 59 KB LDS copy of W1T.
__global__ __launch_bounds__(256) void k_prep(const float* __restrict__ W1,
                                              short* __restrict__ W1F) {
  const int idx = blockIdx.x * 256 + threadIdx.x;     // [0, 28672) = 8*7*64*8
  const int jj = idx & 7, ln = (idx >> 3) & 63;
  const int rest = idx >> 9;                          // ft*7 + k
  const int k = rest % 7, ft = rest / 7;
  const int f = ft * 16 + (ln & 15);
  const int c = k * 32 + (ln >> 4) * 8 + jj;
  W1F[idx] = (c < CIN) ? f2bf(W1[(size_t)c * HID + f]) : (short)0;
}

// ---------- k_gin: 832-thr block (13 waves) per batch; LDS ~20 KB -> 2 blocks/CU ----------
// r6's ft-loop verbatim; W1 B-frags from global W1F (coalesced); ingest over all 13 waves.
__global__ __launch_bounds__(832) void k_gin(const float* __restrict__ x,
                                             const int* __restrict__ adj,
                                             const short* __restrict__ W1Fg,
                                             const float* __restrict__ b1,
                                             const float* __restrict__ W2,
                                             const float* __restrict__ b2,
                                             const float* __restrict__ eps1p,
                                             const float* __restrict__ eps2p,
                                             float* __restrict__ out) {
  __shared__ __align__(16) short    ls_slab[16 * IPY];   //  7,424 B  y-slab for current ft
  __shared__ __align__(16) unsigned ls_bits[KCH * 224];  //  6,272 B  [wd][j]
  __shared__ __align__(16) int      ls_degp[4 * 224];    //  3,584 B  per-segment deg partials
  __shared__ __align__(16) float    ls_deg[224];         //    896 B
  __shared__ __align__(16) float    ls_w2b1[384];        //  1,536 B  [0,128)=b1, [128,384)=W2
  __shared__               float    ls_part[NWAVE][2];   //    104 B     total ~19.8 KB

  const int b    = blockIdx.x;
  const int tid  = threadIdx.x;
  const int wave = tid >> 6, lane = tid & 63;
  const int lq   = lane >> 4, lm = lane & 15;
  const int* adjb = adj + (size_t)b * NNODE * NNODE;

  // ---- issue tiny param loads early (latency hides under ingest) ----
  float wv = 0.f;
  if (tid < 384) wv = (tid < 128) ? b1[tid] : W2[tid - 128];

  // ============ phase A.1: adj ingest, 28 jobs (wd,seg) over 13 waves ============
  // Per job: 32 batched loads (one latency exposure), pack bits + 1 ballot/row for deg.
  for (int jb = wave; jb < 28; jb += NWAVE) {
    const int wd = jb >> 2, seg = jb & 3;
    const int rmax = (wd == 6) ? 8 : 32;
    const int j  = seg * 64 + lane;
    const int jc = min(j, NNODE - 1);
    const unsigned jv = (j < NNODE) ? 1u : 0u;
    int v[32];
#pragma unroll
    for (int t = 0; t < 32; ++t)                        // 32 loads in flight (rows clamped)
      v[t] = adjb[(size_t)min(wd * 32 + t, NNODE - 1) * NNODE + jc];
    unsigned wacc = 0;
#pragma unroll
    for (int t = 0; t < 32; ++t) {                      // pack + ballot-deg partial
      const unsigned bit = (unsigned)v[t] & jv & (unsigned)(t < rmax ? 1 : 0);
      wacc |= bit << t;
      const int dg = __popcll(__ballot(bit != 0u));
      if (lane == 0 && wd * 32 + t < NNODE) ls_degp[seg * 224 + wd * 32 + t] = dg;
    }
    if (j < 224 && (seg < 3 || lane < 32))              // bank = j%32: conflict-free
      ls_bits[wd * 224 + j] = wacc;                     // pad cols (jv=0) store 0
  }

  // ============ phase A.2: x gather -> af, slab-pad zero, params -> LDS ============
  sh8 af[KCH];                                          // x fragments (28 VGPR, persistent)
  {
    f32x4 px0[KCH], px1[KCH];
    const float* xr = x + (size_t)b * NNODE * CIN + (size_t)min(wave * 16 + lm, NNODE - 1) * CIN;
#pragma unroll
    for (int k = 0; k < KCH; ++k) {
      const int c0 = k * 32 + lq * 8;
      f32x4 z = {0.f, 0.f, 0.f, 0.f};
      px0[k] = z; px1[k] = z;
      if (c0 < CIN) { px0[k] = *(const f32x4*)(xr + c0); px1[k] = *(const f32x4*)(xr + c0 + 4); }
    }
    if (tid < 64) {                                     // zero slab cols 200-231 (once)
      const int rw = tid >> 2, p = tid & 3;
      sh8 z = {0, 0, 0, 0, 0, 0, 0, 0};
      *(sh8*)&ls_slab[rw * IPY + 200 + p * 8] = z;
    }
    if (tid < 384) ls_w2b1[tid] = wv;
#pragma unroll
    for (int k = 0; k < KCH; ++k) {                     // px dies here
      sh8 a;
#pragma unroll
      for (int jj = 0; jj < 4; ++jj) { a[jj] = f2bf(px0[k][jj]); a[4 + jj] = f2bf(px1[k][jj]); }
      af[k] = a;
    }
  }
  __syncthreads();

  // ---- deg finalize (reads other waves' partials; consumed only after ft-loop) ----
  if (tid < NNODE)
    ls_deg[tid] = (float)(ls_degp[tid] + ls_degp[224 + tid] +
                          ls_degp[448 + tid] + ls_degp[672 + tid]);

  // ================= fused ft loop: phase1(slab) | barrier | phase2(agg+MLP2) =================
  const float e1 = eps1p[0], e2 = eps2p[0];
  const int j = wave * 16 + lm;                         // this wave's jt == mt == wave
  unsigned by[KCH];                                     // adjacency bytes (7 VGPR)
#pragma unroll
  for (int k = 0; k < KCH; ++k) by[k] = (ls_bits[k * 224 + j] >> (lq * 8)) & 0xFFu;
  float ga = 0.f, gb = 0.f;

  for (int ft = 0; ft < 8; ++ft) {
    const int fb = ft * 16;
    {
      // ---- phase 1: y-slab[f-rel][m] for this ft; B-frags coalesced from global W1F ----
      const sh8* wf = (const sh8*)W1Fg + (size_t)ft * KCH * 64;
      f32x4 acc = {0.f, 0.f, 0.f, 0.f};
#pragma unroll
      for (int k = 0; k < KCH; ++k)
        acc = mfma16(af[k], wf[k * 64 + lane], acc);
      sh4 st;                                           // D: n=lm->f_rel, m=lq*4+r
#pragma unroll
      for (int r = 0; r < 4; ++r) st[r] = f2bf(acc[r]);
      *(sh4*)&ls_slab[lm * IPY + wave * 16 + lq * 4] = st;  // col <= 207; cols>=200 see
    }                                                       // zero adjacency bits anyway
    __syncthreads();
    {
      // ---- phase 2: agg over m + eps self-term + MLP2 partial ----
      const short* yr = &ls_slab[lm * IPY];             // conflict-free b128 (2-way)
      f32x4 accP = {0.f, 0.f, 0.f, 0.f};
#pragma unroll
      for (int k = 0; k < KCH; ++k)
        accP = mfma16i(*(const sh8*)(yr + k * 32 + lq * 8), expand8(by[k]), accP);
#pragma unroll
      for (int r = 0; r < 4; ++r) {
        const int f = fb + lq * 4 + r;
        const float yself = bf2f(ls_slab[(lq * 4 + r) * IPY + j]);  // y[f][j]
        const float h = fmaxf(accP[r] + (1.f + e1) * yself + ls_w2b1[f], 0.f);
        ga += h * ls_w2b1[128 + 2 * f];
        gb += h * ls_w2b1[129 + 2 * f];
      }
    }
    __syncthreads();
  }

  // ================= epilogue: j-sum, pooled mean, out =================
  {
    ga += __shfl_xor(ga, 16); ga += __shfl_xor(ga, 32); // sum over lq -> full f-sum per j
    gb += __shfl_xor(gb, 16); gb += __shfl_xor(gb, 32);
    const bool jok = (j < NNODE);
    const float wj = 1.f + e2 + ls_deg[min(j, NNODE - 1)];
    float t0 = jok ? wj * ga : 0.f;
    float t1 = jok ? wj * gb : 0.f;
#pragma unroll
    for (int d = 1; d < 16; d <<= 1) { t0 += __shfl_xor(t0, d); t1 += __shfl_xor(t1, d); }
    if (lane == 0) { ls_part[wave][0] = t0; ls_part[wave][1] = t1; }
  }
  __syncthreads();

  if (tid < 2) {                                        // out fully overwritten, no atomics
    float s = 0.f;
#pragma unroll
    for (int q = 0; q < NWAVE; ++q) s += ls_part[q][tid];
    out[b * 2 + tid] = b2[tid] + s * (1.f / NNODE);
  }
}

extern "C" void kernel_launch(void* const* d_in, const int* in_sizes, int n_in,
                              void* d_out, int out_size, void* d_ws, size_t ws_size,
                              hipStream_t stream) {
  const float* x    = (const float*)d_in[0];
  const int*   adj  = (const int*)d_in[1];
  const float* W1   = (const float*)d_in[2];
  const float* b1   = (const float*)d_in[3];
  const float* W2   = (const float*)d_in[4];
  const float* b2   = (const float*)d_in[5];
  const float* eps1 = (const float*)d_in[6];
  const float* eps2 = (const float*)d_in[7];
  float* out = (float*)d_out;

  short* W1F = (short*)d_ws;                            // 57,344 B fragment-linear W1

  k_prep<<<112, 256, 0, stream>>>(W1, W1F);
  k_gin <<<BATCH, NWAVE * 64, 0, stream>>>(x, adj, W1F, b1, W2, b2, eps1, eps2, out);
}